// Round 1
// baseline (2388.809 us; speedup 1.0000x reference)
//
#include <hip/hip_runtime.h>
#include <math.h>

#define NB 8
#define CTC 1024
#define LL 1024
#define BN_EPS 1e-5f

// ---------------- workspace layout (floats) ----------------
#define OFF_WKQV 0
#define SZ_WKQV (2048*128)
#define OFF_BKQV (OFF_WKQV + SZ_WKQV)
#define SZ_BKQV 2048
#define OFF_WF (OFF_BKQV + SZ_BKQV)
#define SZ_WF (1024*1024)
#define OFF_BF (OFF_WF + SZ_WF)
#define SZ_BF 1024
#define OFF_KQV (OFF_BF + SZ_BF)
#define SZ_KQV (NB*2048*LL)
#define OFF_T2 (OFF_KQV + SZ_KQV)
#define SZ_T2 (NB*CTC*LL)
// total = 26,479,616 floats ~= 106 MB

// ---------------- prep: fold BN into weights/bias ----------------
__global__ void prep_kqv(
    const float* __restrict__ kw, const float* __restrict__ kb, const float* __restrict__ kg,
    const float* __restrict__ kbe, const float* __restrict__ km, const float* __restrict__ kv,
    const float* __restrict__ qw, const float* __restrict__ qb, const float* __restrict__ qg,
    const float* __restrict__ qbe, const float* __restrict__ qm, const float* __restrict__ qv,
    const float* __restrict__ vw, const float* __restrict__ vb, const float* __restrict__ vg,
    const float* __restrict__ vbe, const float* __restrict__ vm, const float* __restrict__ vv,
    float* __restrict__ wf, float* __restrict__ bf)
{
    int idx = blockIdx.x * blockDim.x + threadIdx.x;  // 0 .. 2048*128-1
    int co = idx >> 7, ci = idx & 127;
    const float *w, *b, *g, *be, *m, *v; int r;
    if (co < 512)       { w = kw; b = kb; g = kg; be = kbe; m = km; v = kv; r = co; }
    else if (co < 1024) { w = qw; b = qb; g = qg; be = qbe; m = qm; v = qv; r = co - 512; }
    else                { w = vw; b = vb; g = vg; be = vbe; m = vm; v = vv; r = co - 1024; }
    float inv = g[r] * rsqrtf(v[r] + BN_EPS);
    wf[idx] = w[r * 128 + ci] * inv;
    if (ci == 0) bf[co] = (b[r] - m[r]) * inv + be[r];
}

__global__ void prep_f(
    const float* __restrict__ fw, const float* __restrict__ fb, const float* __restrict__ fg,
    const float* __restrict__ fbe, const float* __restrict__ fm, const float* __restrict__ fv,
    float* __restrict__ wf, float* __restrict__ bf)
{
    int idx = blockIdx.x * blockDim.x + threadIdx.x;  // 0 .. 1024*1024-1
    int co = idx >> 10, ci = idx & 1023;
    float inv = fg[co] * rsqrtf(fv[co] + BN_EPS);
    wf[idx] = fw[idx] * inv;
    if (ci == 0) bf[co] = (fb[co] - fm[co]) * inv + fbe[co];
}

// ---------------- conv kqv: grouped 1x1 conv as GEMM ----------------
// grid (L/64, 2048/32, N), block 256. Each block: 32 co x 64 l, K=128.
__global__ __launch_bounds__(256) void conv_kqv(
    const float* __restrict__ x, const float* __restrict__ wf,
    const float* __restrict__ bf, float* __restrict__ y)
{
    __shared__ float ws_[32][129];
    __shared__ float xs[128][64];
    const int l0  = blockIdx.x * 64;
    const int co0 = blockIdx.y * 32;
    const int n   = blockIdx.z;
    const int tid = threadIdx.x;
    int in_off;
    if (co0 < 512)       in_off = (co0 >> 6) << 7;          // k: 64 co per group
    else if (co0 < 1024) in_off = ((co0 - 512) >> 6) << 7;  // q
    else                 in_off = ((co0 - 1024) >> 7) << 7; // v: 128 co per group

    #pragma unroll
    for (int j = 0; j < 16; ++j) {
        int f = tid + 256 * j; int row = f >> 7, ci = f & 127;
        ws_[row][ci] = wf[(size_t)(co0 + row) * 128 + ci];
    }
    #pragma unroll
    for (int j = 0; j < 32; ++j) {
        int f = tid + 256 * j; int ci = f >> 6, l = f & 63;
        xs[ci][l] = x[((size_t)n * CTC + in_off + ci) * LL + l0 + l];
    }
    __syncthreads();

    const int cy = tid >> 3;        // 0..31 co within tile
    const int lx = (tid & 7) * 8;   // 0..56 l within tile
    float acc[8] = {0.f,0.f,0.f,0.f,0.f,0.f,0.f,0.f};
    for (int ci = 0; ci < 128; ++ci) {
        float wv = ws_[cy][ci];
        float4 a = *(const float4*)&xs[ci][lx];
        float4 c = *(const float4*)&xs[ci][lx + 4];
        acc[0] += wv * a.x; acc[1] += wv * a.y; acc[2] += wv * a.z; acc[3] += wv * a.w;
        acc[4] += wv * c.x; acc[5] += wv * c.y; acc[6] += wv * c.z; acc[7] += wv * c.w;
    }
    const int co = co0 + cy;
    float bb = bf[co];
    float* yp = &y[((size_t)n * 2048 + co) * LL + l0 + lx];
    float4 o0 = make_float4(acc[0]+bb, acc[1]+bb, acc[2]+bb, acc[3]+bb);
    float4 o1 = make_float4(acc[4]+bb, acc[5]+bb, acc[6]+bb, acc[7]+bb);
    *(float4*)&yp[0] = o0;
    *(float4*)&yp[4] = o1;
}

// ---------------- fused flash attention + residual ----------------
// grid (L/64, H=16, N), block (64,4). Per block: one (n,h), 64 q columns.
__global__ __launch_bounds__(256) void attn(
    const float* __restrict__ kqv, const float* __restrict__ tokens,
    float* __restrict__ t2)
{
    __shared__ float Qs[32][64];
    __shared__ float Ks[32][64];
    __shared__ float Vs[64][64];
    __shared__ float Ss[64][64];
    const int q0 = blockIdx.x * 64;
    const int h  = blockIdx.y;
    const int n  = blockIdx.z;
    const int tx = threadIdx.x;     // q column 0..63
    const int ty = threadIdx.y;     // dv block / k-row block 0..3
    const int tid = ty * 64 + tx;

    const float* kb = kqv + ((size_t)n * 2048 + h * 32) * LL;
    const float* qb = kqv + ((size_t)n * 2048 + 512 + h * 32) * LL;
    const float* vb = kqv + ((size_t)n * 2048 + 1024 + h * 64) * LL;

    #pragma unroll
    for (int j = 0; j < 8; ++j) {
        int f = tid + 256 * j; int d = f >> 6, l = f & 63;
        Qs[d][l] = qb[(size_t)d * LL + q0 + l];
    }

    float acc[16];
    #pragma unroll
    for (int i = 0; i < 16; ++i) acc[i] = 0.f;
    float mrun = -1e30f, lrun = 0.f;
    const float scale = 1.0f / 32.0f;  // 1/sqrt(1024)

    for (int kt = 0; kt < 16; ++kt) {
        const int k0 = kt * 64;
        __syncthreads();  // protect Ks/Vs/Ss from previous iteration
        #pragma unroll
        for (int j = 0; j < 8; ++j) {
            int f = tid + 256 * j; int d = f >> 6, l = f & 63;
            Ks[d][l] = kb[(size_t)d * LL + k0 + l];
        }
        #pragma unroll
        for (int j = 0; j < 16; ++j) {
            int f = tid + 256 * j; int d = f >> 6, l = f & 63;
            Vs[d][l] = vb[(size_t)d * LL + k0 + l];
        }
        __syncthreads();

        // S tile: this thread computes k rows [ty*16, ty*16+16) for q=tx
        {
            float s[16];
            #pragma unroll
            for (int i = 0; i < 16; ++i) s[i] = 0.f;
            const int kk0 = ty * 16;
            for (int d = 0; d < 32; ++d) {
                float qv = Qs[d][tx];
                #pragma unroll
                for (int i = 0; i < 16; i += 4) {
                    float4 k4 = *(const float4*)&Ks[d][kk0 + i];
                    s[i]   += k4.x * qv; s[i+1] += k4.y * qv;
                    s[i+2] += k4.z * qv; s[i+3] += k4.w * qv;
                }
            }
            #pragma unroll
            for (int i = 0; i < 16; ++i) Ss[kk0 + i][tx] = s[i] * scale;
        }
        __syncthreads();

        // online softmax over the 64 new k rows (each thread: its q column)
        float tmax = -1e30f;
        for (int kk = 0; kk < 64; ++kk) tmax = fmaxf(tmax, Ss[kk][tx]);
        float mnew = fmaxf(mrun, tmax);
        float corr = __expf(mrun - mnew);
        lrun *= corr;
        #pragma unroll
        for (int i = 0; i < 16; ++i) acc[i] *= corr;
        mrun = mnew;

        // PV: acc[dv] += sum_k p[k] * V[dv][k], k chunked by 16
        for (int c = 0; c < 4; ++c) {
            float p[16];
            #pragma unroll
            for (int j = 0; j < 16; ++j) {
                p[j] = __expf(Ss[c * 16 + j][tx] - mnew);
                lrun += p[j];
            }
            #pragma unroll
            for (int i = 0; i < 16; ++i) {
                const float* vrow = &Vs[ty * 16 + i][c * 16];
                #pragma unroll
                for (int j = 0; j < 16; j += 4) {
                    float4 v4 = *(const float4*)&vrow[j];
                    acc[i] += p[j] * v4.x + p[j+1] * v4.y + p[j+2] * v4.z + p[j+3] * v4.w;
                }
            }
        }
    }

    float rl = 1.0f / lrun;
    #pragma unroll
    for (int i = 0; i < 16; ++i) {
        size_t off = ((size_t)n * CTC + h * 64 + ty * 16 + i) * LL + q0 + tx;
        t2[off] = tokens[off] + acc[i] * rl;
    }
}

// ---------------- ff conv (groups=1) + residual ----------------
// grid (L/64, 1024/32, N), block 256. K=1024 in 8 chunks of 128.
__global__ __launch_bounds__(256) void conv_f(
    const float* __restrict__ t2, const float* __restrict__ wf,
    const float* __restrict__ bf, float* __restrict__ out)
{
    __shared__ float ws_[32][129];
    __shared__ float xs[128][64];
    const int l0  = blockIdx.x * 64;
    const int co0 = blockIdx.y * 32;
    const int n   = blockIdx.z;
    const int tid = threadIdx.x;
    const int cy  = tid >> 3;
    const int lx  = (tid & 7) * 8;
    float acc[8] = {0.f,0.f,0.f,0.f,0.f,0.f,0.f,0.f};

    for (int kc = 0; kc < 8; ++kc) {
        __syncthreads();
        #pragma unroll
        for (int j = 0; j < 16; ++j) {
            int f = tid + 256 * j; int row = f >> 7, ci = f & 127;
            ws_[row][ci] = wf[(size_t)(co0 + row) * 1024 + kc * 128 + ci];
        }
        #pragma unroll
        for (int j = 0; j < 32; ++j) {
            int f = tid + 256 * j; int ci = f >> 6, l = f & 63;
            xs[ci][l] = t2[((size_t)n * CTC + kc * 128 + ci) * LL + l0 + l];
        }
        __syncthreads();
        for (int ci = 0; ci < 128; ++ci) {
            float wv = ws_[cy][ci];
            float4 a = *(const float4*)&xs[ci][lx];
            float4 c = *(const float4*)&xs[ci][lx + 4];
            acc[0] += wv * a.x; acc[1] += wv * a.y; acc[2] += wv * a.z; acc[3] += wv * a.w;
            acc[4] += wv * c.x; acc[5] += wv * c.y; acc[6] += wv * c.z; acc[7] += wv * c.w;
        }
    }
    const int co = co0 + cy;
    float bb = bf[co];
    size_t off = ((size_t)n * CTC + co) * LL + l0 + lx;
    #pragma unroll
    for (int j = 0; j < 8; ++j) out[off + j] = acc[j] + bb + t2[off + j];
}

// ---------------- launch ----------------
extern "C" void kernel_launch(void* const* d_in, const int* in_sizes, int n_in,
                              void* d_out, int out_size, void* d_ws, size_t ws_size,
                              hipStream_t stream) {
    const float* tokens = (const float*)d_in[0];
    const float* kw  = (const float*)d_in[1];
    const float* kb_ = (const float*)d_in[2];
    const float* kg  = (const float*)d_in[3];
    const float* kbe = (const float*)d_in[4];
    const float* km  = (const float*)d_in[5];
    const float* kv  = (const float*)d_in[6];
    const float* qw  = (const float*)d_in[7];
    const float* qb_ = (const float*)d_in[8];
    const float* qg  = (const float*)d_in[9];
    const float* qbe = (const float*)d_in[10];
    const float* qm  = (const float*)d_in[11];
    const float* qv  = (const float*)d_in[12];
    const float* vw  = (const float*)d_in[13];
    const float* vb_ = (const float*)d_in[14];
    const float* vg  = (const float*)d_in[15];
    const float* vbe = (const float*)d_in[16];
    const float* vm  = (const float*)d_in[17];
    const float* vv  = (const float*)d_in[18];
    const float* fw  = (const float*)d_in[19];
    const float* fb_ = (const float*)d_in[20];
    const float* fg  = (const float*)d_in[21];
    const float* fbe = (const float*)d_in[22];
    const float* fm  = (const float*)d_in[23];
    const float* fv  = (const float*)d_in[24];

    float* ws = (float*)d_ws;
    float* WKQV = ws + OFF_WKQV;
    float* BKQV = ws + OFF_BKQV;
    float* WF   = ws + OFF_WF;
    float* BF   = ws + OFF_BF;
    float* KQV  = ws + OFF_KQV;
    float* T2   = ws + OFF_T2;
    float* out  = (float*)d_out;

    prep_kqv<<<1024, 256, 0, stream>>>(kw, kb_, kg, kbe, km, kv,
                                       qw, qb_, qg, qbe, qm, qv,
                                       vw, vb_, vg, vbe, vm, vv,
                                       WKQV, BKQV);
    prep_f<<<4096, 256, 0, stream>>>(fw, fb_, fg, fbe, fm, fv, WF, BF);
    conv_kqv<<<dim3(16, 64, NB), 256, 0, stream>>>(tokens, WKQV, BKQV, KQV);
    attn<<<dim3(16, 16, NB), dim3(64, 4), 0, stream>>>(KQV, tokens, T2);
    conv_f<<<dim3(16, 32, NB), 256, 0, stream>>>(T2, WF, BF, out);
}

// Round 2
// 345.239 us; speedup vs baseline: 6.9193x; 6.9193x over previous
//
#include <hip/hip_runtime.h>
#include <math.h>

#define NB 8
#define BN_EPS 1e-5f
#define CEXP 0.04508422002778011f  // log2(e)/32

typedef __attribute__((ext_vector_type(4))) float f32x4;
typedef __attribute__((ext_vector_type(8))) short short8;

__device__ __forceinline__ ushort f2bf(float f) {
    union { float f; unsigned u; } v; v.f = f;
    unsigned r = v.u + 0x7fffu + ((v.u >> 16) & 1u);
    return (ushort)(r >> 16);
}
__device__ __forceinline__ float bf2f(ushort h) {
    union { unsigned u; float f; } v; v.u = ((unsigned)h) << 16;
    return v.f;
}

// ---------------- workspace layout (bytes) ----------------
#define O_WKQV   0u          // ushort[2048*128]
#define O_BKQV   524288u     // float[2048]
#define O_WFH    532480u     // ushort[1024*1024]
#define O_WFL    2629632u    // ushort[1024*1024]
#define O_BF     4726784u    // float[1024]
#define O_TOKT   4730880u    // ushort[8*1024*1024]  (reused as t2T_hi after conv_kqv)
#define O_T2TL   21508096u   // ushort[8*1024*1024]
#define O_KT     38285312u   // ushort[8*16*1024*32]
#define O_QT     46673920u   // ushort[8*16*1024*32]
#define O_V      55062528u   // ushort[8*16*64*1024]
#define O_T2     71839744u   // float[8*1024*1024]
// end = 105394176 bytes

// ---------------- prep: fold BN, cast weights to bf16 ----------------
__global__ void prep_kqv(
    const float* __restrict__ kw, const float* __restrict__ kb, const float* __restrict__ kg,
    const float* __restrict__ kbe, const float* __restrict__ km, const float* __restrict__ kv,
    const float* __restrict__ qw, const float* __restrict__ qb, const float* __restrict__ qg,
    const float* __restrict__ qbe, const float* __restrict__ qm, const float* __restrict__ qv,
    const float* __restrict__ vw, const float* __restrict__ vb, const float* __restrict__ vg,
    const float* __restrict__ vbe, const float* __restrict__ vm, const float* __restrict__ vv,
    ushort* __restrict__ wf, float* __restrict__ bf)
{
    int idx = blockIdx.x * blockDim.x + threadIdx.x;  // 0 .. 2048*128-1
    int co = idx >> 7, ci = idx & 127;
    const float *w, *b, *g, *be, *m, *vr; int r;
    if (co < 512)       { w = kw; b = kb; g = kg; be = kbe; m = km; vr = kv; r = co; }
    else if (co < 1024) { w = qw; b = qb; g = qg; be = qbe; m = qm; vr = qv; r = co - 512; }
    else                { w = vw; b = vb; g = vg; be = vbe; m = vm; vr = vv; r = co - 1024; }
    float inv = g[r] * rsqrtf(vr[r] + BN_EPS);
    wf[idx] = f2bf(w[r * 128 + ci] * inv);
    if (ci == 0) bf[co] = (b[r] - m[r]) * inv + be[r];
}

__global__ void prep_f(
    const float* __restrict__ fw, const float* __restrict__ fb, const float* __restrict__ fg,
    const float* __restrict__ fbe, const float* __restrict__ fm, const float* __restrict__ fv,
    ushort* __restrict__ wfh, ushort* __restrict__ wfl, float* __restrict__ bf)
{
    int idx = blockIdx.x * blockDim.x + threadIdx.x;  // 0 .. 1024*1024-1
    int co = idx >> 10, ci = idx & 1023;
    float inv = fg[co] * rsqrtf(fv[co] + BN_EPS);
    float w = fw[idx] * inv;
    ushort hi = f2bf(w);
    wfh[idx] = hi;
    wfl[idx] = f2bf(w - bf2f(hi));
    if (ci == 0) bf[co] = (fb[co] - fm[co]) * inv + fbe[co];
}

// ---------------- transpose tokens: f32 [n][c][l] -> bf16 [n][l][c] ----------------
// grid (16 lblk, 16 cblk, NB), block 256
__global__ __launch_bounds__(256) void transpose_tokens(
    const float* __restrict__ x, ushort* __restrict__ xt)
{
    __shared__ float Ts[64][68];
    const int l0 = blockIdx.x * 64, c0 = blockIdx.y * 64, n = blockIdx.z;
    const int tid = threadIdx.x;
    #pragma unroll
    for (int r = 0; r < 4; ++r) {
        int idx = tid + 256 * r;
        int ci = idx >> 4, li4 = (idx & 15) * 4;
        float4 v4 = *(const float4*)&x[((size_t)(n * 1024 + c0 + ci)) * 1024 + l0 + li4];
        *(float4*)&Ts[ci][li4] = v4;
    }
    __syncthreads();
    #pragma unroll
    for (int r = 0; r < 2; ++r) {
        int idx = tid + 256 * r;          // 0..511
        int lr = idx >> 3, oc = idx & 7;  // row l (0..63), c octet
        union { ushort u[8]; uint4 v; } pk;
        #pragma unroll
        for (int i = 0; i < 8; ++i) pk.u[i] = f2bf(Ts[oc * 8 + i][lr]);
        *(uint4*)&xt[((size_t)(n * 1024 + l0 + lr)) * 1024 + c0 + oc * 8] = pk.v;
    }
}

// ---------------- conv_kqv: bf16 MFMA GEMM, writes KT/QT (transposed) + V ----------------
// grid (8 lblk, 32 coblk, NB), block 256 (4 waves, 2x2). Tile 64co x 128l, K=128.
__global__ __launch_bounds__(256) void conv_kqv_mfma(
    const ushort* __restrict__ xt, const ushort* __restrict__ wq,
    const float* __restrict__ bq,
    ushort* __restrict__ KT, ushort* __restrict__ QT, ushort* __restrict__ V)
{
    __shared__ ushort Ws[64 * 128];   // [co][ci], 16 slots/row, swizzle slot^(row&15)
    __shared__ ushort Xs[128 * 128];  // [l][ci]
    const int l0 = blockIdx.x * 128, co0 = blockIdx.y * 64, n = blockIdx.z;
    const int tid = threadIdx.x;
    const int wid = tid >> 6, ln = tid & 63, g = ln >> 4, ln15 = ln & 15;
    const int wm = wid >> 1, wn = wid & 1;

    int in_off;
    if (co0 < 512)       in_off = (co0 >> 6) << 7;
    else if (co0 < 1024) in_off = ((co0 - 512) >> 6) << 7;
    else                 in_off = ((co0 - 1024) >> 7) << 7;

    #pragma unroll
    for (int r = 0; r < 4; ++r) {
        int c = tid + 256 * r; int row = c >> 4, slot = c & 15;
        uint4 v4 = *(const uint4*)&wq[(size_t)(co0 + row) * 128 + slot * 8];
        *(uint4*)&Ws[row * 128 + ((slot ^ (row & 15)) << 3)] = v4;
    }
    #pragma unroll
    for (int r = 0; r < 8; ++r) {
        int c = tid + 256 * r; int row = c >> 4, slot = c & 15;
        uint4 v4 = *(const uint4*)&xt[((size_t)(n * 1024 + l0 + row)) * 1024 + in_off + slot * 8];
        *(uint4*)&Xs[row * 128 + ((slot ^ (row & 15)) << 3)] = v4;
    }
    __syncthreads();

    f32x4 acc[2][4];
    #pragma unroll
    for (int mf = 0; mf < 2; ++mf)
        #pragma unroll
        for (int nf = 0; nf < 4; ++nf) acc[mf][nf] = (f32x4){0.f, 0.f, 0.f, 0.f};

    #pragma unroll
    for (int ks = 0; ks < 4; ++ks) {
        short8 a[2], b[4];
        #pragma unroll
        for (int mf = 0; mf < 2; ++mf) {
            int row = wm * 32 + mf * 16 + ln15;
            int slot = ks * 4 + g;
            a[mf] = *(const short8*)&Ws[row * 128 + (((slot ^ (row & 15))) << 3)];
        }
        #pragma unroll
        for (int nf = 0; nf < 4; ++nf) {
            int row = wn * 64 + nf * 16 + ln15;
            int slot = ks * 4 + g;
            b[nf] = *(const short8*)&Xs[row * 128 + (((slot ^ (row & 15))) << 3)];
        }
        #pragma unroll
        for (int mf = 0; mf < 2; ++mf)
            #pragma unroll
            for (int nf = 0; nf < 4; ++nf)
                acc[mf][nf] = __builtin_amdgcn_mfma_f32_16x16x32_bf16(a[mf], b[nf], acc[mf][nf], 0, 0, 0);
    }

    // epilogue: add bias, scatter to KT/QT ([n][h][l][32]) or V ([n][h][64][1024])
    #pragma unroll
    for (int mf = 0; mf < 2; ++mf) {
        int m0 = wm * 32 + mf * 16 + g * 4;   // + r
        int co = co0 + m0;
        float bb[4];
        #pragma unroll
        for (int r = 0; r < 4; ++r) bb[r] = bq[co + r];
        #pragma unroll
        for (int nf = 0; nf < 4; ++nf) {
            int l = l0 + wn * 64 + nf * 16 + ln15;
            float v0 = acc[mf][nf][0] + bb[0];
            float v1 = acc[mf][nf][1] + bb[1];
            float v2 = acc[mf][nf][2] + bb[2];
            float v3 = acc[mf][nf][3] + bb[3];
            if (co0 < 512) {
                int h = co >> 5, d = m0 & 31;
                union { ushort u[4]; uint2 v; } pk;
                pk.u[0] = f2bf(v0); pk.u[1] = f2bf(v1); pk.u[2] = f2bf(v2); pk.u[3] = f2bf(v3);
                *(uint2*)&KT[(((size_t)(n * 16 + h)) * 1024 + l) * 32 + d] = pk.v;
            } else if (co0 < 1024) {
                int cq = co - 512; int h = cq >> 5, d = (m0) & 31;
                union { ushort u[4]; uint2 v; } pk;
                pk.u[0] = f2bf(v0); pk.u[1] = f2bf(v1); pk.u[2] = f2bf(v2); pk.u[3] = f2bf(v3);
                *(uint2*)&QT[(((size_t)(n * 16 + h)) * 1024 + l) * 32 + d] = pk.v;
            } else {
                int cv = co - 1024; int h = cv >> 6, dv = cv & 63;
                size_t base = (((size_t)(n * 16 + h)) * 64 + dv) * 1024 + l;
                V[base]          = f2bf(v0);
                V[base + 1024]   = f2bf(v1);
                V[base + 2048]   = f2bf(v2);
                V[base + 3072]   = f2bf(v3);
            }
        }
    }
}

// ---------------- attention: MFMA S + online softmax + MFMA PV + residual ----------------
// grid (16 qblk, 16 h, NB), block 256 = 4 independent waves; wave q-range = 16.
__global__ __launch_bounds__(256) void attn_mfma(
    const ushort* __restrict__ KT, const ushort* __restrict__ QT, const ushort* __restrict__ V,
    const float* __restrict__ tokens, float* __restrict__ t2,
    ushort* __restrict__ t2th, ushort* __restrict__ t2tl)
{
    __shared__ ushort Pt[4][16 * 80];  // per-wave P^T [q][k], pad row to 80 halves
    const int tid = threadIdx.x;
    const int wid = tid >> 6, ln = tid & 63, g = ln >> 4, ln15 = ln & 15;
    const int n = blockIdx.z, h = blockIdx.y;
    const int q0 = blockIdx.x * 64 + wid * 16;

    const ushort* KTh = KT + ((size_t)(n * 16 + h)) * 1024 * 32;
    const ushort* QTh = QT + ((size_t)(n * 16 + h)) * 1024 * 32;
    const ushort* Vh  = V  + ((size_t)(n * 16 + h)) * 64 * 1024;

    short8 qf = *(const short8*)&QTh[(q0 + ln15) * 32 + g * 8];

    f32x4 acc[4];
    #pragma unroll
    for (int mf = 0; mf < 4; ++mf) acc[mf] = (f32x4){0.f, 0.f, 0.f, 0.f};
    float m_run = -1e30f, l_run = 0.f;
    const f32x4 zz = {0.f, 0.f, 0.f, 0.f};
    ushort* pt = &Pt[wid][0];

    for (int kt = 0; kt < 16; ++kt) {
        const int k0 = kt * 64;
        f32x4 s[4];
        #pragma unroll
        for (int mf = 0; mf < 4; ++mf) {
            short8 kf = *(const short8*)&KTh[(k0 + mf * 16 + ln15) * 32 + g * 8];
            s[mf] = __builtin_amdgcn_mfma_f32_16x16x32_bf16(kf, qf, zz, 0, 0, 0);
        }
        float tm = -1e30f;
        #pragma unroll
        for (int mf = 0; mf < 4; ++mf) {
            tm = fmaxf(tm, fmaxf(fmaxf(s[mf][0], s[mf][1]), fmaxf(s[mf][2], s[mf][3])));
        }
        tm = fmaxf(tm, __shfl_xor(tm, 16));
        tm = fmaxf(tm, __shfl_xor(tm, 32));
        float mnew = fmaxf(m_run, tm);
        float corr = __builtin_amdgcn_exp2f((m_run - mnew) * CEXP);
        l_run *= corr;
        #pragma unroll
        for (int mf = 0; mf < 4; ++mf) acc[mf] *= corr;
        m_run = mnew;

        #pragma unroll
        for (int mf = 0; mf < 4; ++mf) {
            float p0 = __builtin_amdgcn_exp2f((s[mf][0] - mnew) * CEXP);
            float p1 = __builtin_amdgcn_exp2f((s[mf][1] - mnew) * CEXP);
            float p2 = __builtin_amdgcn_exp2f((s[mf][2] - mnew) * CEXP);
            float p3 = __builtin_amdgcn_exp2f((s[mf][3] - mnew) * CEXP);
            l_run += p0 + p1 + p2 + p3;
            union { ushort u[4]; uint2 v; } pk;
            pk.u[0] = f2bf(p0); pk.u[1] = f2bf(p1); pk.u[2] = f2bf(p2); pk.u[3] = f2bf(p3);
            *(uint2*)&pt[ln15 * 80 + mf * 16 + g * 4] = pk.v;
        }
        // PV (same wave wrote Pt -> compiler inserts lgkmcnt ordering)
        #pragma unroll
        for (int ks = 0; ks < 2; ++ks) {
            short8 pf = *(const short8*)&pt[ln15 * 80 + ks * 32 + g * 8];
            #pragma unroll
            for (int mf = 0; mf < 4; ++mf) {
                short8 vf = *(const short8*)&Vh[(mf * 16 + ln15) * 1024 + k0 + ks * 32 + g * 8];
                acc[mf] = __builtin_amdgcn_mfma_f32_16x16x32_bf16(vf, pf, acc[mf], 0, 0, 0);
            }
        }
    }

    l_run += __shfl_xor(l_run, 16);
    l_run += __shfl_xor(l_run, 32);
    float rl = 1.0f / l_run;

    const int l = q0 + ln15;
    #pragma unroll
    for (int mf = 0; mf < 4; ++mf) {
        int dv = mf * 16 + g * 4;
        int c = h * 64 + dv;
        size_t base = ((size_t)(n * 1024 + c)) * 1024 + l;
        union { ushort u[4]; uint2 v; } ph, pl;
        #pragma unroll
        for (int r = 0; r < 4; ++r) {
            float val = acc[mf][r] * rl + tokens[base + (size_t)r * 1024];
            t2[base + (size_t)r * 1024] = val;
            ushort hh = f2bf(val);
            ph.u[r] = hh;
            pl.u[r] = f2bf(val - bf2f(hh));
        }
        size_t tb = ((size_t)(n * 1024 + l)) * 1024 + c;
        *(uint2*)&t2th[tb] = ph.v;
        *(uint2*)&t2tl[tb] = pl.v;
    }
}

// ---------------- conv_f: hi/lo split bf16 MFMA GEMM + bias + residual ----------------
// grid (8 lblk, 8 coblk, NB), block 256 (4 waves 2x2). Tile 128co x 128l, BK=64, 16 iters.
__global__ __launch_bounds__(256) void conv_f_mfma(
    const ushort* __restrict__ xh, const ushort* __restrict__ xl,
    const ushort* __restrict__ wh, const ushort* __restrict__ wl,
    const float* __restrict__ bf, const float* __restrict__ t2,
    float* __restrict__ out)
{
    __shared__ ushort AsH[128 * 64], AsL[128 * 64];  // [co][ci] 8 slots/row, swizzle slot^(row&7)
    __shared__ ushort XsH[128 * 64], XsL[128 * 64];  // [l][ci]
    const int l0 = blockIdx.x * 128, co0 = blockIdx.y * 128, n = blockIdx.z;
    const int tid = threadIdx.x;
    const int wid = tid >> 6, ln = tid & 63, g = ln >> 4, ln15 = ln & 15;
    const int wm = wid >> 1, wn = wid & 1;

    f32x4 acc[4][4];
    #pragma unroll
    for (int mf = 0; mf < 4; ++mf)
        #pragma unroll
        for (int nf = 0; nf < 4; ++nf) acc[mf][nf] = (f32x4){0.f, 0.f, 0.f, 0.f};

    for (int kt = 0; kt < 16; ++kt) {
        const int k0 = kt * 64;
        __syncthreads();
        #pragma unroll
        for (int r = 0; r < 4; ++r) {
            int c = tid + 256 * r; int row = c >> 3, slot = c & 7;
            int sw = row * 64 + ((slot ^ (row & 7)) << 3);
            uint4 va = *(const uint4*)&wh[(size_t)(co0 + row) * 1024 + k0 + slot * 8];
            *(uint4*)&AsH[sw] = va;
            uint4 vb = *(const uint4*)&wl[(size_t)(co0 + row) * 1024 + k0 + slot * 8];
            *(uint4*)&AsL[sw] = vb;
            size_t gx = ((size_t)(n * 1024 + l0 + row)) * 1024 + k0 + slot * 8;
            uint4 vc = *(const uint4*)&xh[gx];
            *(uint4*)&XsH[sw] = vc;
            uint4 vd = *(const uint4*)&xl[gx];
            *(uint4*)&XsL[sw] = vd;
        }
        __syncthreads();

        #pragma unroll
        for (int ks = 0; ks < 2; ++ks) {
            short8 ah[4], al[4], bh[4], bl[4];
            #pragma unroll
            for (int mf = 0; mf < 4; ++mf) {
                int row = wm * 64 + mf * 16 + ln15;
                int slot = ks * 4 + g;
                int off = row * 64 + ((slot ^ (row & 7)) << 3);
                ah[mf] = *(const short8*)&AsH[off];
                al[mf] = *(const short8*)&AsL[off];
            }
            #pragma unroll
            for (int nf = 0; nf < 4; ++nf) {
                int row = wn * 64 + nf * 16 + ln15;
                int slot = ks * 4 + g;
                int off = row * 64 + ((slot ^ (row & 7)) << 3);
                bh[nf] = *(const short8*)&XsH[off];
                bl[nf] = *(const short8*)&XsL[off];
            }
            #pragma unroll
            for (int mf = 0; mf < 4; ++mf)
                #pragma unroll
                for (int nf = 0; nf < 4; ++nf) {
                    acc[mf][nf] = __builtin_amdgcn_mfma_f32_16x16x32_bf16(ah[mf], bh[nf], acc[mf][nf], 0, 0, 0);
                    acc[mf][nf] = __builtin_amdgcn_mfma_f32_16x16x32_bf16(ah[mf], bl[nf], acc[mf][nf], 0, 0, 0);
                    acc[mf][nf] = __builtin_amdgcn_mfma_f32_16x16x32_bf16(al[mf], bh[nf], acc[mf][nf], 0, 0, 0);
                }
        }
    }

    #pragma unroll
    for (int mf = 0; mf < 4; ++mf) {
        int co = co0 + wm * 64 + mf * 16 + g * 4;
        #pragma unroll
        for (int r = 0; r < 4; ++r) {
            float bb = bf[co + r];
            #pragma unroll
            for (int nf = 0; nf < 4; ++nf) {
                int l = l0 + wn * 64 + nf * 16 + ln15;
                size_t off = ((size_t)(n * 1024 + co + r)) * 1024 + l;
                out[off] = acc[mf][nf][r] + bb + t2[off];
            }
        }
    }
}

// ---------------- launch ----------------
extern "C" void kernel_launch(void* const* d_in, const int* in_sizes, int n_in,
                              void* d_out, int out_size, void* d_ws, size_t ws_size,
                              hipStream_t stream) {
    const float* tokens = (const float*)d_in[0];
    const float* kw  = (const float*)d_in[1];
    const float* kb_ = (const float*)d_in[2];
    const float* kg  = (const float*)d_in[3];
    const float* kbe = (const float*)d_in[4];
    const float* km  = (const float*)d_in[5];
    const float* kv  = (const float*)d_in[6];
    const float* qw  = (const float*)d_in[7];
    const float* qb_ = (const float*)d_in[8];
    const float* qg  = (const float*)d_in[9];
    const float* qbe = (const float*)d_in[10];
    const float* qm  = (const float*)d_in[11];
    const float* qv  = (const float*)d_in[12];
    const float* vw  = (const float*)d_in[13];
    const float* vb_ = (const float*)d_in[14];
    const float* vg  = (const float*)d_in[15];
    const float* vbe = (const float*)d_in[16];
    const float* vm  = (const float*)d_in[17];
    const float* vv  = (const float*)d_in[18];
    const float* fw  = (const float*)d_in[19];
    const float* fb_ = (const float*)d_in[20];
    const float* fg  = (const float*)d_in[21];
    const float* fbe = (const float*)d_in[22];
    const float* fm  = (const float*)d_in[23];
    const float* fv  = (const float*)d_in[24];

    char* ws = (char*)d_ws;
    ushort* WKQV = (ushort*)(ws + O_WKQV);
    float*  BKQV = (float*)(ws + O_BKQV);
    ushort* WFH  = (ushort*)(ws + O_WFH);
    ushort* WFL  = (ushort*)(ws + O_WFL);
    float*  BF   = (float*)(ws + O_BF);
    ushort* TOKT = (ushort*)(ws + O_TOKT);   // also t2T_hi
    ushort* T2TL = (ushort*)(ws + O_T2TL);
    ushort* KT   = (ushort*)(ws + O_KT);
    ushort* QT   = (ushort*)(ws + O_QT);
    ushort* Vb   = (ushort*)(ws + O_V);
    float*  T2   = (float*)(ws + O_T2);
    float*  out  = (float*)d_out;

    prep_kqv<<<1024, 256, 0, stream>>>(kw, kb_, kg, kbe, km, kv,
                                       qw, qb_, qg, qbe, qm, qv,
                                       vw, vb_, vg, vbe, vm, vv,
                                       WKQV, BKQV);
    prep_f<<<4096, 256, 0, stream>>>(fw, fb_, fg, fbe, fm, fv, WFH, WFL, BF);
    transpose_tokens<<<dim3(16, 16, NB), 256, 0, stream>>>(tokens, TOKT);
    conv_kqv_mfma<<<dim3(8, 32, NB), 256, 0, stream>>>(TOKT, WKQV, BKQV, KT, QT, Vb);
    attn_mfma<<<dim3(16, 16, NB), 256, 0, stream>>>(KT, QT, Vb, tokens, T2, TOKT, T2TL);
    conv_f_mfma<<<dim3(8, 8, NB), 256, 0, stream>>>(TOKT, T2TL, WFH, WFL, BF, T2, out);
}

// Round 3
// 271.888 us; speedup vs baseline: 8.7860x; 1.2698x over previous
//
#include <hip/hip_runtime.h>
#include <hip/hip_bf16.h>
#include <math.h>

#define NB 8
#define BN_EPS 1e-5f
#define CEXP 0.04508422002778011f  // log2(e)/32

typedef __attribute__((ext_vector_type(4))) float f32x4;
typedef __attribute__((ext_vector_type(8))) short short8;

__device__ __forceinline__ float bf2f(ushort h) {
    union { unsigned u; float f; } v; v.u = ((unsigned)h) << 16;
    return v.f;
}
__device__ __forceinline__ ushort f2bfu(float f) {
    __hip_bfloat16 h = __float2bfloat16(f);
    union { __hip_bfloat16 h; ushort u; } c; c.h = h; return c.u;
}
__device__ __forceinline__ void gld16(const ushort* g, ushort* l) {
    __builtin_amdgcn_global_load_lds(
        (const __attribute__((address_space(1))) void*)g,
        (__attribute__((address_space(3))) void*)l, 16, 0, 0);
}

// ---------------- workspace layout (bytes) ----------------
#define O_WKQV   0u          // ushort[2048*128]
#define O_BKQV   524288u     // float[2048]
#define O_WFH    532480u     // ushort[1024*1024]
#define O_WFL    2629632u    // ushort[1024*1024]
#define O_BF     4726784u    // float[1024]
#define O_TOKT   4730880u    // ushort[8*1024*1024]  (reused as t2T_hi after conv_kqv)
#define O_T2TL   21508096u   // ushort[8*1024*1024]
#define O_KT     38285312u   // ushort[8*16*1024*32]
#define O_QT     46673920u   // ushort[8*16*1024*32]
#define O_V      55062528u   // ushort[8*16*64*1024]
#define O_T2     71839744u   // float[8*1024*1024]

// ---------------- prep: fold BN, cast weights to bf16 ----------------
__global__ void prep_kqv(
    const float* __restrict__ kw, const float* __restrict__ kb, const float* __restrict__ kg,
    const float* __restrict__ kbe, const float* __restrict__ km, const float* __restrict__ kv,
    const float* __restrict__ qw, const float* __restrict__ qb, const float* __restrict__ qg,
    const float* __restrict__ qbe, const float* __restrict__ qm, const float* __restrict__ qv,
    const float* __restrict__ vw, const float* __restrict__ vb, const float* __restrict__ vg,
    const float* __restrict__ vbe, const float* __restrict__ vm, const float* __restrict__ vv,
    ushort* __restrict__ wf, float* __restrict__ bf)
{
    int idx = blockIdx.x * blockDim.x + threadIdx.x;  // 0 .. 2048*128-1
    int co = idx >> 7, ci = idx & 127;
    const float *w, *b, *g, *be, *m, *vr; int r;
    if (co < 512)       { w = kw; b = kb; g = kg; be = kbe; m = km; vr = kv; r = co; }
    else if (co < 1024) { w = qw; b = qb; g = qg; be = qbe; m = qm; vr = qv; r = co - 512; }
    else                { w = vw; b = vb; g = vg; be = vbe; m = vm; vr = vv; r = co - 1024; }
    float inv = g[r] * rsqrtf(vr[r] + BN_EPS);
    wf[idx] = f2bfu(w[r * 128 + ci] * inv);
    if (ci == 0) bf[co] = (b[r] - m[r]) * inv + be[r];
}

__global__ void prep_f(
    const float* __restrict__ fw, const float* __restrict__ fb, const float* __restrict__ fg,
    const float* __restrict__ fbe, const float* __restrict__ fm, const float* __restrict__ fv,
    ushort* __restrict__ wfh, ushort* __restrict__ wfl, float* __restrict__ bf)
{
    int idx = blockIdx.x * blockDim.x + threadIdx.x;  // 0 .. 1024*1024-1
    int co = idx >> 10, ci = idx & 1023;
    float inv = fg[co] * rsqrtf(fv[co] + BN_EPS);
    float w = fw[idx] * inv;
    ushort hi = f2bfu(w);
    wfh[idx] = hi;
    wfl[idx] = f2bfu(w - bf2f(hi));
    if (ci == 0) bf[co] = (fb[co] - fm[co]) * inv + fbe[co];
}

// ---------------- transpose tokens: f32 [n][c][l] -> bf16 [n][l][c] ----------------
__global__ __launch_bounds__(256) void transpose_tokens(
    const float* __restrict__ x, ushort* __restrict__ xt)
{
    __shared__ float Ts[64][68];
    const int l0 = blockIdx.x * 64, c0 = blockIdx.y * 64, n = blockIdx.z;
    const int tid = threadIdx.x;
    #pragma unroll
    for (int r = 0; r < 4; ++r) {
        int idx = tid + 256 * r;
        int ci = idx >> 4, li4 = (idx & 15) * 4;
        float4 v4 = *(const float4*)&x[((size_t)(n * 1024 + c0 + ci)) * 1024 + l0 + li4];
        *(float4*)&Ts[ci][li4] = v4;
    }
    __syncthreads();
    #pragma unroll
    for (int r = 0; r < 2; ++r) {
        int idx = tid + 256 * r;          // 0..511
        int lr = idx >> 3, oc = idx & 7;  // row l (0..63), c octet
        union { ushort u[8]; uint4 v; } pk;
        #pragma unroll
        for (int i = 0; i < 8; ++i) pk.u[i] = f2bfu(Ts[oc * 8 + i][lr]);
        *(uint4*)&xt[((size_t)(n * 1024 + l0 + lr)) * 1024 + c0 + oc * 8] = pk.v;
    }
}

// ---------------- conv_kqv: bf16 MFMA GEMM, writes KT/QT (transposed) + V ----------------
__global__ __launch_bounds__(256) void conv_kqv_mfma(
    const ushort* __restrict__ xt, const ushort* __restrict__ wq,
    const float* __restrict__ bq,
    ushort* __restrict__ KT, ushort* __restrict__ QT, ushort* __restrict__ V)
{
    __shared__ ushort Ws[64 * 128];
    __shared__ ushort Xs[128 * 128];
    const int l0 = blockIdx.x * 128, co0 = blockIdx.y * 64, n = blockIdx.z;
    const int tid = threadIdx.x;
    const int wid = tid >> 6, ln = tid & 63, g = ln >> 4, ln15 = ln & 15;
    const int wm = wid >> 1, wn = wid & 1;

    int in_off;
    if (co0 < 512)       in_off = (co0 >> 6) << 7;
    else if (co0 < 1024) in_off = ((co0 - 512) >> 6) << 7;
    else                 in_off = ((co0 - 1024) >> 7) << 7;

    #pragma unroll
    for (int r = 0; r < 4; ++r) {
        int c = tid + 256 * r; int row = c >> 4, slot = c & 15;
        uint4 v4 = *(const uint4*)&wq[(size_t)(co0 + row) * 128 + slot * 8];
        *(uint4*)&Ws[row * 128 + ((slot ^ (row & 15)) << 3)] = v4;
    }
    #pragma unroll
    for (int r = 0; r < 8; ++r) {
        int c = tid + 256 * r; int row = c >> 4, slot = c & 15;
        uint4 v4 = *(const uint4*)&xt[((size_t)(n * 1024 + l0 + row)) * 1024 + in_off + slot * 8];
        *(uint4*)&Xs[row * 128 + ((slot ^ (row & 15)) << 3)] = v4;
    }
    __syncthreads();

    f32x4 acc[2][4];
    #pragma unroll
    for (int mf = 0; mf < 2; ++mf)
        #pragma unroll
        for (int nf = 0; nf < 4; ++nf) acc[mf][nf] = (f32x4){0.f, 0.f, 0.f, 0.f};

    #pragma unroll
    for (int ks = 0; ks < 4; ++ks) {
        short8 a[2], b[4];
        #pragma unroll
        for (int mf = 0; mf < 2; ++mf) {
            int row = wm * 32 + mf * 16 + ln15;
            int slot = ks * 4 + g;
            a[mf] = *(const short8*)&Ws[row * 128 + (((slot ^ (row & 15))) << 3)];
        }
        #pragma unroll
        for (int nf = 0; nf < 4; ++nf) {
            int row = wn * 64 + nf * 16 + ln15;
            int slot = ks * 4 + g;
            b[nf] = *(const short8*)&Xs[row * 128 + (((slot ^ (row & 15))) << 3)];
        }
        #pragma unroll
        for (int mf = 0; mf < 2; ++mf)
            #pragma unroll
            for (int nf = 0; nf < 4; ++nf)
                acc[mf][nf] = __builtin_amdgcn_mfma_f32_16x16x32_bf16(a[mf], b[nf], acc[mf][nf], 0, 0, 0);
    }

    #pragma unroll
    for (int mf = 0; mf < 2; ++mf) {
        int m0 = wm * 32 + mf * 16 + g * 4;
        int co = co0 + m0;
        float bb[4];
        #pragma unroll
        for (int r = 0; r < 4; ++r) bb[r] = bq[co + r];
        #pragma unroll
        for (int nf = 0; nf < 4; ++nf) {
            int l = l0 + wn * 64 + nf * 16 + ln15;
            float v0 = acc[mf][nf][0] + bb[0];
            float v1 = acc[mf][nf][1] + bb[1];
            float v2 = acc[mf][nf][2] + bb[2];
            float v3 = acc[mf][nf][3] + bb[3];
            if (co0 < 512) {
                int h = co >> 5, d = m0 & 31;
                union { ushort u[4]; uint2 v; } pk;
                pk.u[0] = f2bfu(v0); pk.u[1] = f2bfu(v1); pk.u[2] = f2bfu(v2); pk.u[3] = f2bfu(v3);
                *(uint2*)&KT[(((size_t)(n * 16 + h)) * 1024 + l) * 32 + d] = pk.v;
            } else if (co0 < 1024) {
                int cq = co - 512; int h = cq >> 5, d = m0 & 31;
                union { ushort u[4]; uint2 v; } pk;
                pk.u[0] = f2bfu(v0); pk.u[1] = f2bfu(v1); pk.u[2] = f2bfu(v2); pk.u[3] = f2bfu(v3);
                *(uint2*)&QT[(((size_t)(n * 16 + h)) * 1024 + l) * 32 + d] = pk.v;
            } else {
                int cv = co - 1024; int h = cv >> 6, dv = cv & 63;
                size_t base = (((size_t)(n * 16 + h)) * 64 + dv) * 1024 + l;
                V[base]          = f2bfu(v0);
                V[base + 1024]   = f2bfu(v1);
                V[base + 2048]   = f2bfu(v2);
                V[base + 3072]   = f2bfu(v3);
            }
        }
    }
}

// ---------------- attention: LDS-staged K/V dbuf, no-max softmax, MFMA ----------------
// grid (8 qblk, 16 h, NB), block 256 (4 waves). Wave owns 32 q; block 128 q.
// LDS: Vs 16K + Ks 8K + Pt 16K = 40K -> 4 blocks/CU.
__global__ __launch_bounds__(256) void attn_mfma(
    const ushort* __restrict__ KT, const ushort* __restrict__ QT, const ushort* __restrict__ V,
    const float* __restrict__ tokens, float* __restrict__ t2,
    ushort* __restrict__ t2th, ushort* __restrict__ t2tl)
{
    __shared__ ushort Vs[2][64 * 64];   // [dv][k], 16B-slot swizzled: slot ^= dv&7
    __shared__ ushort Ks[2][64 * 32];   // [k][d], linear (64B rows -> conflict-free)
    __shared__ ushort Pt[4][32 * 64];   // per-wave [q][k], slot ^= q&7
    const int tid = threadIdx.x;
    const int wid = tid >> 6, ln = tid & 63, g = ln >> 4, ln15 = ln & 15;
    const int n = blockIdx.z, h = blockIdx.y;
    const int qw = blockIdx.x * 128 + wid * 32;
    const int sw7 = ln15 & 7;

    const ushort* KTh = KT + ((size_t)(n * 16 + h)) * 1024 * 32;
    const ushort* QTh = QT + ((size_t)(n * 16 + h)) * 1024 * 32;
    const ushort* Vh  = V  + ((size_t)(n * 16 + h)) * 64 * 1024;

    short8 qfr[2];
    qfr[0] = *(const short8*)&QTh[(qw + ln15) * 32 + g * 8];
    qfr[1] = *(const short8*)&QTh[(qw + 16 + ln15) * 32 + g * 8];

    // staging geometry (per-lane)
    const int vrow = ln >> 3, vcol = (ln & 7) ^ vrow;   // V: pre-swizzled source
    const int krow = ln >> 2, kcol = ln & 3;            // K: linear
    const ushort* vsrc = Vh + (size_t)(wid * 16 + vrow) * 1024 + vcol * 8;
    const ushort* ksrc = KTh + (size_t)(wid * 16 + krow) * 32 + kcol * 8;

    // prologue: stage k-tile 0 into buffer 0
    gld16(vsrc,            &Vs[0][wid * 1024]);
    gld16(vsrc + 8 * 1024, &Vs[0][wid * 1024 + 512]);
    gld16(ksrc,            &Ks[0][wid * 512]);
    __syncthreads();

    f32x4 acc[4][2];
    #pragma unroll
    for (int mf = 0; mf < 4; ++mf)
        #pragma unroll
        for (int qf = 0; qf < 2; ++qf) acc[mf][qf] = (f32x4){0.f, 0.f, 0.f, 0.f};
    float l_run[2] = {0.f, 0.f};
    const f32x4 zz = {0.f, 0.f, 0.f, 0.f};
    ushort* pt = &Pt[wid][0];

    for (int kt = 0; kt < 16; ++kt) {
        const int cur = kt & 1;
        if (kt < 15) {
            const int nxt = cur ^ 1;
            const int k0n = (kt + 1) * 64;
            gld16(vsrc + k0n,            &Vs[nxt][wid * 1024]);
            gld16(vsrc + k0n + 8 * 1024, &Vs[nxt][wid * 1024 + 512]);
            gld16(ksrc + k0n * 32,       &Ks[nxt][wid * 512]);
        }
        short8 kf[4];
        #pragma unroll
        for (int mf = 0; mf < 4; ++mf)
            kf[mf] = *(const short8*)&Ks[cur][(mf * 16 + ln15) * 32 + g * 8];

        #pragma unroll
        for (int qf = 0; qf < 2; ++qf) {
            f32x4 s[4];
            #pragma unroll
            for (int mf = 0; mf < 4; ++mf)
                s[mf] = __builtin_amdgcn_mfma_f32_16x16x32_bf16(kf[mf], qfr[qf], zz, 0, 0, 0);
            float lacc = 0.f;
            #pragma unroll
            for (int mf = 0; mf < 4; ++mf) {
                float p0 = __builtin_amdgcn_exp2f(s[mf][0] * CEXP);
                float p1 = __builtin_amdgcn_exp2f(s[mf][1] * CEXP);
                float p2 = __builtin_amdgcn_exp2f(s[mf][2] * CEXP);
                float p3 = __builtin_amdgcn_exp2f(s[mf][3] * CEXP);
                lacc += (p0 + p1) + (p2 + p3);
                union { ushort u[4]; uint2 v; } pk;
                pk.u[0] = f2bfu(p0); pk.u[1] = f2bfu(p1);
                pk.u[2] = f2bfu(p2); pk.u[3] = f2bfu(p3);
                // element k = mf*16 + g*4 + r lives in 16B-slot (mf*2 + (g>>1)), sub (g&1)*4
                *(uint2*)&pt[(qf * 16 + ln15) * 64 +
                             (((mf * 2 + (g >> 1)) ^ sw7) << 3) + (g & 1) * 4] = pk.v;
            }
            l_run[qf] += lacc;
        }

        #pragma unroll
        for (int ks = 0; ks < 2; ++ks) {
            short8 vf[4];
            #pragma unroll
            for (int mf = 0; mf < 4; ++mf)
                vf[mf] = *(const short8*)&Vs[cur][(mf * 16 + ln15) * 64 +
                                                  (((ks * 4 + g) ^ sw7) << 3)];
            #pragma unroll
            for (int qf = 0; qf < 2; ++qf) {
                short8 pf = *(const short8*)&pt[(qf * 16 + ln15) * 64 +
                                                (((ks * 4 + g) ^ sw7) << 3)];
                #pragma unroll
                for (int mf = 0; mf < 4; ++mf)
                    acc[mf][qf] = __builtin_amdgcn_mfma_f32_16x16x32_bf16(vf[mf], pf, acc[mf][qf], 0, 0, 0);
            }
        }
        __syncthreads();
    }

    #pragma unroll
    for (int qf = 0; qf < 2; ++qf) {
        float l = l_run[qf];
        l += __shfl_xor(l, 16);
        l += __shfl_xor(l, 32);
        float rl = 1.0f / l;
        const int lq = qw + qf * 16 + ln15;
        #pragma unroll
        for (int mf = 0; mf < 4; ++mf) {
            int dv = mf * 16 + g * 4;
            int c = h * 64 + dv;
            size_t base = ((size_t)(n * 1024 + c)) * 1024 + lq;
            union { ushort u[4]; uint2 v; } ph, pl;
            #pragma unroll
            for (int r = 0; r < 4; ++r) {
                float val = acc[mf][qf][r] * rl + tokens[base + (size_t)r * 1024];
                t2[base + (size_t)r * 1024] = val;
                ushort hh = f2bfu(val);
                ph.u[r] = hh;
                pl.u[r] = f2bfu(val - bf2f(hh));
            }
            size_t tb = ((size_t)(n * 1024 + lq)) * 1024 + c;
            *(uint2*)&t2th[tb] = ph.v;
            *(uint2*)&t2tl[tb] = pl.v;
        }
    }
}

// ---------------- conv_f: hi/lo split MFMA GEMM, gl_lds dbuf BK=32 ----------------
// grid (8 lblk, 8 coblk, NB), block 256 (4 waves 2x2). Tile 128co x 128l, 32 kt.
// LDS: 4 arrays x 8K x 2buf = 64K -> 2 blocks/CU.
__global__ __launch_bounds__(256) void conv_f_mfma(
    const ushort* __restrict__ xh, const ushort* __restrict__ xl,
    const ushort* __restrict__ wh, const ushort* __restrict__ wl,
    const float* __restrict__ bf, const float* __restrict__ t2,
    float* __restrict__ out)
{
    __shared__ ushort AsH[2][128 * 32], AsL[2][128 * 32];
    __shared__ ushort XsH[2][128 * 32], XsL[2][128 * 32];
    const int l0 = blockIdx.x * 128, co0 = blockIdx.y * 128, n = blockIdx.z;
    const int tid = threadIdx.x;
    const int wid = tid >> 6, ln = tid & 63, g = ln >> 4, ln15 = ln & 15;
    const int wm = wid >> 1, wn = wid & 1;
    const int srow = ln >> 2, scol = ln & 3;  // 64B rows, linear (conflict-free)

    f32x4 acc[4][4];
    #pragma unroll
    for (int mf = 0; mf < 4; ++mf)
        #pragma unroll
        for (int nf = 0; nf < 4; ++nf) acc[mf][nf] = (f32x4){0.f, 0.f, 0.f, 0.f};

    auto stage = [&](int k0, int b) {
        #pragma unroll
        for (int j = 0; j < 2; ++j) {
            const int rr = wid * 32 + j * 16 + srow;
            const int ld = wid * 1024 + j * 512;
            const size_t wo = (size_t)(co0 + rr) * 1024 + k0 + scol * 8;
            const size_t xo = ((size_t)(n * 1024 + l0 + rr)) * 1024 + k0 + scol * 8;
            gld16(wh + wo, &AsH[b][ld]);
            gld16(wl + wo, &AsL[b][ld]);
            gld16(xh + xo, &XsH[b][ld]);
            gld16(xl + xo, &XsL[b][ld]);
        }
    };

    stage(0, 0);
    __syncthreads();

    for (int kt = 0; kt < 32; ++kt) {
        const int cur = kt & 1;
        if (kt < 31) stage((kt + 1) * 32, cur ^ 1);
        short8 ah[4], al[4], bh[4], bl[4];
        #pragma unroll
        for (int mf = 0; mf < 4; ++mf) {
            const int off = (wm * 64 + mf * 16 + ln15) * 32 + g * 8;
            ah[mf] = *(const short8*)&AsH[cur][off];
            al[mf] = *(const short8*)&AsL[cur][off];
        }
        #pragma unroll
        for (int nf = 0; nf < 4; ++nf) {
            const int off = (wn * 64 + nf * 16 + ln15) * 32 + g * 8;
            bh[nf] = *(const short8*)&XsH[cur][off];
            bl[nf] = *(const short8*)&XsL[cur][off];
        }
        #pragma unroll
        for (int mf = 0; mf < 4; ++mf)
            #pragma unroll
            for (int nf = 0; nf < 4; ++nf) {
                acc[mf][nf] = __builtin_amdgcn_mfma_f32_16x16x32_bf16(ah[mf], bh[nf], acc[mf][nf], 0, 0, 0);
                acc[mf][nf] = __builtin_amdgcn_mfma_f32_16x16x32_bf16(ah[mf], bl[nf], acc[mf][nf], 0, 0, 0);
                acc[mf][nf] = __builtin_amdgcn_mfma_f32_16x16x32_bf16(al[mf], bh[nf], acc[mf][nf], 0, 0, 0);
            }
        __syncthreads();
    }

    #pragma unroll
    for (int mf = 0; mf < 4; ++mf) {
        int co = co0 + wm * 64 + mf * 16 + g * 4;
        #pragma unroll
        for (int r = 0; r < 4; ++r) {
            float bb = bf[co + r];
            #pragma unroll
            for (int nf = 0; nf < 4; ++nf) {
                int l = l0 + wn * 64 + nf * 16 + ln15;
                size_t off = ((size_t)(n * 1024 + co + r)) * 1024 + l;
                out[off] = acc[mf][nf][r] + bb + t2[off];
            }
        }
    }
}

// ---------------- launch ----------------
extern "C" void kernel_launch(void* const* d_in, const int* in_sizes, int n_in,
                              void* d_out, int out_size, void* d_ws, size_t ws_size,
                              hipStream_t stream) {
    const float* tokens = (const float*)d_in[0];
    const float* kw  = (const float*)d_in[1];
    const float* kb_ = (const float*)d_in[2];
    const float* kg  = (const float*)d_in[3];
    const float* kbe = (const float*)d_in[4];
    const float* km  = (const float*)d_in[5];
    const float* kv  = (const float*)d_in[6];
    const float* qw  = (const float*)d_in[7];
    const float* qb_ = (const float*)d_in[8];
    const float* qg  = (const float*)d_in[9];
    const float* qbe = (const float*)d_in[10];
    const float* qm  = (const float*)d_in[11];
    const float* qv  = (const float*)d_in[12];
    const float* vw  = (const float*)d_in[13];
    const float* vb_ = (const float*)d_in[14];
    const float* vg  = (const float*)d_in[15];
    const float* vbe = (const float*)d_in[16];
    const float* vm  = (const float*)d_in[17];
    const float* vv  = (const float*)d_in[18];
    const float* fw  = (const float*)d_in[19];
    const float* fb_ = (const float*)d_in[20];
    const float* fg  = (const float*)d_in[21];
    const float* fbe = (const float*)d_in[22];
    const float* fm  = (const float*)d_in[23];
    const float* fv  = (const float*)d_in[24];

    char* ws = (char*)d_ws;
    ushort* WKQV = (ushort*)(ws + O_WKQV);
    float*  BKQV = (float*)(ws + O_BKQV);
    ushort* WFH  = (ushort*)(ws + O_WFH);
    ushort* WFL  = (ushort*)(ws + O_WFL);
    float*  BF   = (float*)(ws + O_BF);
    ushort* TOKT = (ushort*)(ws + O_TOKT);   // also t2T_hi
    ushort* T2TL = (ushort*)(ws + O_T2TL);
    ushort* KT   = (ushort*)(ws + O_KT);
    ushort* QT   = (ushort*)(ws + O_QT);
    ushort* Vb   = (ushort*)(ws + O_V);
    float*  T2   = (float*)(ws + O_T2);
    float*  out  = (float*)d_out;

    prep_kqv<<<1024, 256, 0, stream>>>(kw, kb_, kg, kbe, km, kv,
                                       qw, qb_, qg, qbe, qm, qv,
                                       vw, vb_, vg, vbe, vm, vv,
                                       WKQV, BKQV);
    prep_f<<<4096, 256, 0, stream>>>(fw, fb_, fg, fbe, fm, fv, WFH, WFL, BF);
    transpose_tokens<<<dim3(16, 16, NB), 256, 0, stream>>>(tokens, TOKT);
    conv_kqv_mfma<<<dim3(8, 32, NB), 256, 0, stream>>>(TOKT, WKQV, BKQV, KT, QT, Vb);
    attn_mfma<<<dim3(8, 16, NB), 256, 0, stream>>>(KT, QT, Vb, tokens, T2, TOKT, T2TL);
    conv_f_mfma<<<dim3(8, 8, NB), 256, 0, stream>>>(TOKT, T2TL, WFH, WFL, BF, T2, out);
}